// Round 17
// baseline (59.654 us; speedup 1.0000x reference)
//
#include <hip/hip_runtime.h>

namespace {

constexpr int kB = 8, kO = 128, kI = 128, kD = 1024;
constexpr long kOutAttnOff = (long)kB * kO * kD;   // 1,048,576 floats

typedef __attribute__((ext_vector_type(8))) short short8;  // 8 bf16 = 4 VGPR
typedef __attribute__((ext_vector_type(4))) float f32x4;
typedef __attribute__((ext_vector_type(2))) float f32x2;
typedef __attribute__((ext_vector_type(2))) unsigned u32x2;

__device__ __forceinline__ float leaky(float x) { return fmaxf(x, 0.01f * x); }

// fp32 -> bf16 round-to-nearest-even
__device__ __forceinline__ short f2bf(float f) {
    unsigned u = __builtin_bit_cast(unsigned, f);
    u += 0x7FFFu + ((u >> 16) & 1u);
    return (short)(u >> 16);
}
// short8 of bf16 -> 8 f32
__device__ __forceinline__ void b8tofs(const short8 v, float* f) {
    const unsigned* u = (const unsigned*)&v;
#pragma unroll
    for (int j = 0; j < 4; ++j) {
        f[2 * j]     = __builtin_bit_cast(float, u[j] << 16);
        f[2 * j + 1] = __builtin_bit_cast(float, u[j] & 0xffff0000u);
    }
}
// two short8 (same d-slice, rows j and j+64) -> f32x2 pairs {c_i, c_i64}
__device__ __forceinline__ void bpair(const short8 a, const short8 b, f32x2* p) {
    float fa[8], fb[8];
    b8tofs(a, fa); b8tofs(b, fb);
#pragma unroll
    for (int j = 0; j < 8; ++j) p[j] = f32x2{fa[j], fb[j]};
}
__device__ __forceinline__ f32x2 vabs2(f32x2 x) {
    u32x2 u = __builtin_bit_cast(u32x2, x);
    u &= 0x7fffffffu;
    return __builtin_bit_cast(f32x2, u);
}

// async global->LDS, 16B per lane. LDS dest = wave-uniform base + lane*16.
__device__ __forceinline__ void gll16(const void* g, void* l) {
    __builtin_amdgcn_global_load_lds(
        (const __attribute__((address_space(1))) int*)g,
        (__attribute__((address_space(3))) int*)l, 16, 0, 0);
}

// ---------------------------------------------------------------------------
// All input conversions in ONE kernel (r12/r16 verbatim).
// ---------------------------------------------------------------------------
__global__ __launch_bounds__(256)
void conv_all(const float* __restrict__ output, const float* __restrict__ context,
              const float* __restrict__ w1, const float* __restrict__ w2,
              const float* __restrict__ lin,
              short* __restrict__ ob16, short* __restrict__ cb16,
              short* __restrict__ w1t, short* __restrict__ w2t,
              short* __restrict__ lint)
{
    __shared__ float T[64][68];
    const int bid = blockIdx.x, tid = threadIdx.x;

    if (bid < 1024) {                       // straight convert, 8 floats/thread
        const int idx = bid * 256 + tid;
        const float* src; short* dst; int i;
        if (idx < (1 << 17)) { src = output;  dst = ob16; i = idx; }
        else                 { src = context; dst = cb16; i = idx - (1 << 17); }
        const float4* s4 = (const float4*)src + (long)i * 2;
        const float4 v0 = s4[0], v1 = s4[1];
        short8 r;
        r[0] = f2bf(v0.x); r[1] = f2bf(v0.y); r[2] = f2bf(v0.z); r[3] = f2bf(v0.w);
        r[4] = f2bf(v1.x); r[5] = f2bf(v1.y); r[6] = f2bf(v1.z); r[7] = f2bf(v1.w);
        *(short8*)(dst + (long)i * 8) = r;
        return;
    }

    const int tb = bid - 1024;
    const float* src; short* dst; long C, R; int t2;
    if (tb < 256)      { src = w1;  dst = w1t;  R = 1024; C = 1024; t2 = tb; }
    else if (tb < 512) { src = w2;  dst = w2t;  R = 1024; C = 1024; t2 = tb - 256; }
    else               { src = lin; dst = lint; R = 2048; C = 1024; t2 = tb - 512; }
    const int tr = t2 >> 4, tc = t2 & 15;
    const int r = tid >> 2, q = tid & 3;

    const float* s = src + (long)(tr * 64 + r) * C + tc * 64 + q * 16;
    const float4 a0 = ((const float4*)s)[0];
    const float4 a1 = ((const float4*)s)[1];
    const float4 a2 = ((const float4*)s)[2];
    const float4 a3 = ((const float4*)s)[3];
    *(float4*)&T[r][q * 16 + 0]  = a0;
    *(float4*)&T[r][q * 16 + 4]  = a1;
    *(float4*)&T[r][q * 16 + 8]  = a2;
    *(float4*)&T[r][q * 16 + 12] = a3;
    __syncthreads();

    short8 o0, o1;
#pragma unroll
    for (int j = 0; j < 8; ++j)  o0[j] = f2bf(T[q * 16 + j][r]);
#pragma unroll
    for (int j = 0; j < 8; ++j)  o1[j] = f2bf(T[q * 16 + 8 + j][r]);
    short* dp = dst + (long)(tc * 64 + r) * R + tr * 64 + q * 16;
    *(short8*)dp       = o0;
    *((short8*)dp + 1) = o1;
}

// ---------------------------------------------------------------------------
// Fused independent-GEMM job table (r12/r16 structure): 64x64 tiles, 1024
// blocks, 32KB LDS dbuf, gll16 + XOR chunk swizzle, XCD-aware tile order.
// ONE change vs r16: __launch_bounds__(256, 5) -> 5 blocks/CU (LDS 5x32KB =
// 160KB exactly; VGPR ~68 << 102 cap) to cover the per-step vmcnt(0) drain.
// ---------------------------------------------------------------------------
__global__ __launch_bounds__(256, 5)
void mm_jobs(const short* __restrict__ ob16, const short* __restrict__ cb16,
             const short* __restrict__ w1t, const short* __restrict__ w2t,
             const short* __restrict__ lint,
             const float* __restrict__ w_b, const float* __restrict__ lin_b,
             float* __restrict__ s_out, short* __restrict__ s_ctx16,
             float* __restrict__ outlin, short* __restrict__ ctxlin)
{
    __shared__ short As[2][64][64];
    __shared__ short Bs[2][64][64];
    const int tid = threadIdx.x;
    const int t = (blockIdx.x & 7) * 128 + (blockIdx.x >> 3);   // XCD swizzle
    const int lane = tid & 63, w = tid >> 6;

    const short *Ap, *Bp;
    int lda, ldb, bm, bn, ldc;
    const float* bias = nullptr;
    float* Cf = nullptr;
    short* Ch = nullptr;

    if (t < 768) {
        const int job = t >> 8, tl = t & 255;
        bm = (tl & 15) * 64;            // m fastest: B n-strip shared on-XCD
        bn = (tl >> 4) * 64;
        lda = 1024; ldb = 1024; ldc = 1024;
        if (job == 0)      { Ap = ob16; Bp = w1t;         bias = w_b;   Cf = s_out;   }
        else if (job == 1) { Ap = ob16; Bp = lint + 1024; ldb = 2048; bias = lin_b; Cf = outlin; }
        else               { Ap = cb16; Bp = w2t;                       Ch = s_ctx16; }
    } else {
        const int tl = t - 768, bz = tl >> 5, t2 = tl & 31;
        bm = (t2 & 15) * 64;            // m = d tiles
        bn = (t2 >> 4) * 64;            // n = i tiles (2)
        Ap = lint; lda = 2048;
        Bp = cb16 + (long)bz * (kI * kD); ldb = 1024;
        Ch = ctxlin + (long)bz * (kD * kI); ldc = 128;
    }

    const int m0 = (w >> 1) * 32, n0 = (w & 1) * 32;
    const int fr = lane & 15, fcol = lane >> 4, sl = lane & 7;
    const int r8 = lane >> 3;
    const int sw8 = ((lane & 7) ^ r8) * 8;   // swizzled source col (shorts)
    const int w16 = w * 16;

    f32x4 acc[2][2] = {};

    auto stage = [&](int buf, int k0) {      // 4 gll16 per wave
        const short* ga = Ap + (long)(bm + w16 + r8) * lda + k0 + sw8;
        gll16(ga,                 &As[buf][w16][0]);
        gll16(ga + 8 * (long)lda, &As[buf][w16 + 8][0]);
        const short* gb = Bp + (long)(bn + w16 + r8) * ldb + k0 + sw8;
        gll16(gb,                 &Bs[buf][w16][0]);
        gll16(gb + 8 * (long)ldb, &Bs[buf][w16 + 8][0]);
    };

    stage(0, 0);
    __syncthreads();
    int cur = 0;
    for (int s = 0; s < 16; ++s) {
        if (s < 15) stage(cur ^ 1, (s + 1) << 6);
#pragma unroll
        for (int ks8 = 0; ks8 < 8; ks8 += 4) {      // ks = 0, 32
            const int sa = ((ks8 + fcol) ^ sl) * 8; // swizzled read col (shorts)
            short8 a[2], b[2];
#pragma unroll
            for (int mi = 0; mi < 2; ++mi)
                a[mi] = *(const short8*)&As[cur][m0 + mi * 16 + fr][sa];
#pragma unroll
            for (int ni = 0; ni < 2; ++ni)
                b[ni] = *(const short8*)&Bs[cur][n0 + ni * 16 + fr][sa];
#pragma unroll
            for (int mi = 0; mi < 2; ++mi)
#pragma unroll
                for (int ni = 0; ni < 2; ++ni)
                    acc[mi][ni] = __builtin_amdgcn_mfma_f32_16x16x32_bf16(
                        a[mi], b[ni], acc[mi][ni], 0, 0, 0);
        }
        __syncthreads();
        cur ^= 1;
    }

    float bv[2] = {0, 0};
    if (bias) {
#pragma unroll
        for (int ni = 0; ni < 2; ++ni) bv[ni] = bias[bn + n0 + ni * 16 + fr];
    }
#pragma unroll
    for (int mi = 0; mi < 2; ++mi)
#pragma unroll
        for (int ni = 0; ni < 2; ++ni)
#pragma unroll
            for (int r = 0; r < 4; ++r) {
                const int row = bm + m0 + mi * 16 + ((lane >> 4) << 2) + r;
                const int col = bn + n0 + ni * 16 + fr;
                const float v = acc[mi][ni][r] + bv[ni];
                if (Ch) Ch[(long)row * ldc + col] = f2bf(v);
                else    Cf[(long)row * ldc + col] = v;
            }
}

// ---------------------------------------------------------------------------
// Fused score + mask + softmax + final GEMM (r16 verbatim — new-best config:
// per-wave counted-vmcnt final GEMM, no per-step barriers there).
// Grid (8, 64) = 512 blocks (o-pairs), 4 waves, ~52.8KB LDS -> 3 blocks/CU.
// ---------------------------------------------------------------------------
__global__ __launch_bounds__(256, 3)
void score_final(const float* __restrict__ s_out, const short* __restrict__ s_ctx16,
                 const float* __restrict__ score_w, const float* __restrict__ score_b,
                 const int* __restrict__ mask, const short* __restrict__ ctxlin,
                 const float* __restrict__ outlin, float* __restrict__ out_main,
                 float* __restrict__ attn_f32)
{
    __shared__ float As[2][1032];                   // 2 o-rows fp32 (8.25KB)
    __shared__ __align__(16) char CsPool[32768];    // 2 x 16KB slots (Cs / B)
    __shared__ short Wsh[1032];                     // score_w bf16 (2KB)
    __shared__ float Ps[4][2][128];                 // sa partials (4KB)
    __shared__ float Psi[4][128];                   // si partials (2KB)
    __shared__ float so_sh[2];
    __shared__ int   Msk[128];
    __shared__ __align__(16) short Pl[16][136];     // P rows padded to 16 (4.25KB)

    short* CsS = (short*)CsPool;                    // slot s: CsS + s*8192 shorts
    const int b   = blockIdx.x;
    const int o0  = blockIdx.y * 2;
    const int tid = threadIdx.x;
    const int wv  = tid >> 6;          // d-quarter (wave-uniform)
    const int ln  = tid & 63;          // i low half; also owns i+64
    const int fr  = ln & 15, fg = ln >> 4;

    const short* crow = s_ctx16 + (long)b * kI * kD;
    auto stageCs = [&](int slot, int dc) {          // 4 gll16 per wave
#pragma unroll
        for (int it = 0; it < 4; ++it) {
            const int rb = wv * 32 + it * 8;        // dest row base (8 rows/call)
            const int r  = rb + (ln >> 3);
            const int sc = (ln & 7) ^ (r & 7);      // swizzled source chunk
            gll16(crow + (long)r * kD + dc + sc * 8, CsS + slot * 8192 + rb * 64);
        }
    };

    stageCs(0, 0);                                  // in flight under prologue

    // ---- prologue: stage As (fp32), Wsh (bf16), Msk; zero Pl ----
    const float* arow = s_out + (long)(b * kO + o0) * kD;
#pragma unroll
    for (int q = 0; q < 2; ++q) {      // 2 rows x 1024 = 512 float4
        const int tq = tid + q * 256;
        const int rr = tq >> 8, c4 = (tq & 255) * 4;
        *(float4*)&As[rr][c4] = *(const float4*)&arow[(long)rr * kD + c4];
    }
    {
        const float4 w4 = *(const float4*)&score_w[tid * 4];
        const unsigned p0 = (unsigned)(unsigned short)f2bf(w4.x)
                          | ((unsigned)(unsigned short)f2bf(w4.y) << 16);
        const unsigned p1 = (unsigned)(unsigned short)f2bf(w4.z)
                          | ((unsigned)(unsigned short)f2bf(w4.w) << 16);
        *(u32x2*)&Wsh[tid * 4] = u32x2{p0, p1};
    }
    if (tid < 128) Msk[tid] = mask[b * kI + tid];
    {
        short* pf = &Pl[0][0];                      // 16*136 = 2176 shorts
        for (int j = tid; j < 272; j += 256) *(short8*)(pf + j * 8) = short8{};
    }
    __syncthreads();                   // slot0 landed; LDS staged

    // ---- so[o] = sum_d s_out[o,d]*w[d]; waves 0,1 ----
    if (wv < 2) {
        const short8 wA = *(const short8*)&Wsh[ln * 16];
        const short8 wB = *(const short8*)&Wsh[ln * 16 + 8];
        float wf[16];
        b8tofs(wA, wf); b8tofs(wB, wf + 8);
        float acc = 0.0f;
#pragma unroll
        for (int q = 0; q < 4; ++q) {
            const float4 av = *(const float4*)&As[wv][ln * 16 + q * 4];
            acc = fmaf(av.x, wf[q*4+0], acc); acc = fmaf(av.y, wf[q*4+1], acc);
            acc = fmaf(av.z, wf[q*4+2], acc); acc = fmaf(av.w, wf[q*4+3], acc);
        }
#pragma unroll
        for (int d = 1; d < 64; d <<= 1) acc += __shfl_xor(acc, d, 64);
        if (ln == 0) so_sh[wv] = acc;
    }

    // ---- main loop: sa[o] = sum |av+c|*w, si = sum c*w; packed (i, i+64) ----
    f32x2 si2{0.0f, 0.0f};
    f32x2 sa2[2] = {f32x2{0.0f, 0.0f}, f32x2{0.0f, 0.0f}};
    const int kb = wv * 16;            // this wave's d-slice within each chunk

    int buf = 0;
    for (int c = 0; c < 16; ++c) {
        const int dc = c * 64;
        if (c < 15) stageCs(buf ^ 1, dc + 64);
        const short* Cb = CsS + buf * 8192;
        const int sc0 = ((wv * 2 + 0) ^ (ln & 7)) * 8;
        const int sc1 = ((wv * 2 + 1) ^ (ln & 7)) * 8;
        const short8 cA0 = *(const short8*)&Cb[ln * 64 + sc0];
        const short8 cA1 = *(const short8*)&Cb[ln * 64 + sc1];
        const short8 cB0 = *(const short8*)&Cb[(ln + 64) * 64 + sc0];
        const short8 cB1 = *(const short8*)&Cb[(ln + 64) * 64 + sc1];
        f32x2 c2[16];
        bpair(cA0, cB0, c2);
        bpair(cA1, cB1, c2 + 8);
        const short8 w0 = *(const short8*)&Wsh[dc + kb];      // broadcast
        const short8 w1 = *(const short8*)&Wsh[dc + kb + 8];
        float wr[16];
        b8tofs(w0, wr); b8tofs(w1, wr + 8);
        float av0[16], av1[16];
#pragma unroll
        for (int q = 0; q < 4; ++q) {
            *(float4*)&av0[q * 4] = *(const float4*)&As[0][dc + kb + q * 4];
            *(float4*)&av1[q * 4] = *(const float4*)&As[1][dc + kb + q * 4];
        }
#pragma unroll
        for (int d = 0; d < 16; ++d) {
            const f32x2 w2 = {wr[d], wr[d]};
            si2 += c2[d] * w2;
            const f32x2 x0 = c2[d] + f32x2{av0[d], av0[d]};
            const f32x2 x1 = c2[d] + f32x2{av1[d], av1[d]};
            sa2[0] += vabs2(x0) * w2;
            sa2[1] += vabs2(x1) * w2;
        }
        __syncthreads();               // drains gll16 vmcnt + protects Cs
        buf ^= 1;
    }

    // ---- stage final-GEMM B slot 0 (hides under partials + softmax) ----
    short* Bsh = (short*)CsPool;                    // [2][64][128] bf16
    const short* ctxb = ctxlin + (long)b * (kD * kI);
    auto stageB = [&](int half, int nc) {           // 4 gll16 per wave
#pragma unroll
        for (int it = 0; it < 4; ++it) {
            const int rb = wv * 16 + it * 4;        // dest row base (4 rows/call)
            const int r  = rb + (ln >> 4);
            const int n  = nc * 64 + r;
            const int sc = (ln & 15) ^ (r & 7);     // swizzled source chunk
            gll16(ctxb + (long)n * kI + sc * 8, Bsh + half * 8192 + rb * kI);
        }
    };
    stageB(0, 0);

#pragma unroll
    for (int o = 0; o < 2; ++o) {
        Ps[wv][o][ln]      = sa2[o].x;
        Ps[wv][o][ln + 64] = sa2[o].y;
    }
    Psi[wv][ln]      = si2.x;
    Psi[wv][ln + 64] = si2.y;
    __syncthreads();                   // partials visible; B slot0 landed

    // ---- combine + mask + softmax; waves 0,1 handle o-rows 0,1 ----
    if (wv < 2) {
        const int ow = wv;
        const float negInf = -__builtin_huge_valf();
        const float sb = score_b[0];
        const float siT0 = Psi[0][ln] + Psi[1][ln] + Psi[2][ln] + Psi[3][ln];
        const float siT1 = Psi[0][ln + 64] + Psi[1][ln + 64]
                         + Psi[2][ln + 64] + Psi[3][ln + 64];
        const float saT0 = Ps[0][ow][ln] + Ps[1][ow][ln]
                         + Ps[2][ow][ln] + Ps[3][ow][ln];
        const float saT1 = Ps[0][ow][ln + 64] + Ps[1][ow][ln + 64]
                         + Ps[2][ow][ln + 64] + Ps[3][ow][ln + 64];
        const float soV = so_sh[ow];
        float s0 = 0.505f * (soV + siT0) + 0.495f * saT0 + sb;
        float s1 = 0.505f * (soV + siT1) + 0.495f * saT1 + sb;
        if (Msk[ln]      != 0) s0 = negInf;
        if (Msk[ln + 64] != 0) s1 = negInf;

        float m = fmaxf(s0, s1);
#pragma unroll
        for (int d = 1; d < 64; d <<= 1) m = fmaxf(m, __shfl_xor(m, d, 64));
        const float e0 = __expf(s0 - m);
        const float e1 = __expf(s1 - m);
        float sum = e0 + e1;
#pragma unroll
        for (int d = 1; d < 64; d <<= 1) sum += __shfl_xor(sum, d, 64);
        const float inv = 1.0f / sum;

        const long rowoff = (long)(b * kO + o0 + ow) * kI;
        const float p0 = e0 * inv, p1 = e1 * inv;
        attn_f32[rowoff + ln]      = p0;
        attn_f32[rowoff + ln + 64] = p1;
        Pl[ow][ln]      = f2bf(p0);
        Pl[ow][ln + 64] = f2bf(p1);
    }
    __syncthreads();                   // Pl visible (drains vmcnt: slot0 ready)

    // ---- final GEMM: 16 steps of 64 n-rows, PER-WAVE barrier-free dbuf.
    // Wave wv writes and reads only B rows wv*16..+15 -> no cross-wave dep.
    // FIFO vmcnt: at iter nc the needed slot's 4 loads are the oldest
    // outstanding; vmcnt(4) retires exactly them (vmcnt(0) at the tail).
    for (int nc = 0; nc < 16; ++nc) {
        if (nc < 15) {
            stageB((nc + 1) & 1, nc + 1);
            asm volatile("s_waitcnt vmcnt(4)" ::: "memory");
        } else {
            asm volatile("s_waitcnt vmcnt(0)" ::: "memory");
        }
        __builtin_amdgcn_sched_barrier(0);
        const short* Bc = Bsh + (nc & 1) * 8192;
        f32x4 acc{};
#pragma unroll
        for (int ks = 0; ks < 4; ++ks) {
            const short8 a = *(const short8*)&Pl[fr][ks * 32 + fg * 8];
            const int sc = ((ks * 4 + fg) ^ (fr & 7)) * 8;
            const short8 bb = *(const short8*)&Bc[(wv * 16 + fr) * kI + sc];
            acc = __builtin_amdgcn_mfma_f32_16x16x32_bf16(a, bb, acc, 0, 0, 0);
        }
        if (fg == 0) {                 // real P-rows are m = 0,1
#pragma unroll
            for (int r = 0; r < 2; ++r) {
                const int n = nc * 64 + wv * 16 + fr;
                const long off = (long)(b * kO + o0 + r) * kD + n;
                out_main[off] = leaky(acc[r] + outlin[off]);
            }
        }
    }
}

} // namespace

extern "C" void kernel_launch(void* const* d_in, const int* in_sizes, int n_in,
                              void* d_out, int out_size, void* d_ws, size_t ws_size,
                              hipStream_t stream)
{
    const float* output  = (const float*)d_in[0];   // [B,O,D]
    const float* context = (const float*)d_in[1];   // [B,I,D]
    const int*   mask    = (const int*)d_in[2];     // [B,I]
    const float* w_out_w = (const float*)d_in[3];   // [D,D]
    const float* w_ctx_w = (const float*)d_in[4];   // [D,D]
    const float* w_b     = (const float*)d_in[5];   // [D]
    const float* score_w = (const float*)d_in[6];   // [D]
    const float* score_b = (const float*)d_in[7];   // scalar
    const float* lin_w   = (const float*)d_in[8];   // [2D,D]
    const float* lin_b   = (const float*)d_in[9];   // [D]

    float* out_main = (float*)d_out;                 // [B,O,D]
    float* out_attn = out_main + kOutAttnOff;        // [B,O,I]
    float* s_out    = out_main;                      // overlay: block reads its 2
                                                     // rows before rewriting them

    char* wp = (char*)d_ws;
    short* s_ctx16 = (short*)wp;  wp += (size_t)2 << 20;  // s_ctx bf16 [B*I][D]
    short* ob16    = (short*)wp;  wp += (size_t)2 << 20;  // output bf16
    short* cb16    = (short*)wp;  wp += (size_t)2 << 20;  // context bf16
    short* w1t     = (short*)wp;  wp += (size_t)2 << 20;  // w_out_w^T bf16
    short* w2t     = (short*)wp;  wp += (size_t)2 << 20;  // w_ctx_w^T bf16
    short* lint    = (short*)wp;  wp += (size_t)4 << 20;  // lin_w^T bf16 [1024][2048]
    float* outlin  = (float*)wp;  wp += (size_t)4 << 20;  // output@lin_bot+lin_b fp32
    short* ctxlin  = (short*)wp;                          // (ctx@lin_top)^T bf16 [b][1024][128]

    const dim3 blk(256);

    // 1) all conversions
    hipLaunchKernelGGL(conv_all, dim3(2048), blk, 0, stream,
        output, context, w_out_w, w_ctx_w, lin_w, ob16, cb16, w1t, w2t, lint);

    // 2) all input-independent GEMMs: 64x64 tiles, 1024 blocks, 5 blocks/CU
    hipLaunchKernelGGL(mm_jobs, dim3(1024), blk, 0, stream,
        ob16, cb16, w1t, w2t, lint, w_b, lin_b, s_out, s_ctx16, outlin, ctxlin);

    // 3) score + softmax + final GEMM fused (512 blocks, 3/CU)
    hipLaunchKernelGGL(score_final, dim3(8, 64), blk, 0, stream,
        s_out, s_ctx16, score_w, score_b, mask, ctxlin, outlin, out_main, out_attn);
}

// Round 18
// 58.111 us; speedup vs baseline: 1.0266x; 1.0266x over previous
//
#include <hip/hip_runtime.h>

namespace {

constexpr int kB = 8, kO = 128, kI = 128, kD = 1024;
constexpr long kOutAttnOff = (long)kB * kO * kD;   // 1,048,576 floats

typedef __attribute__((ext_vector_type(8))) short short8;  // 8 bf16 = 4 VGPR
typedef __attribute__((ext_vector_type(4))) float f32x4;
typedef __attribute__((ext_vector_type(2))) float f32x2;
typedef __attribute__((ext_vector_type(2))) unsigned u32x2;

__device__ __forceinline__ float leaky(float x) { return fmaxf(x, 0.01f * x); }

// fp32 -> bf16 round-to-nearest-even
__device__ __forceinline__ short f2bf(float f) {
    unsigned u = __builtin_bit_cast(unsigned, f);
    u += 0x7FFFu + ((u >> 16) & 1u);
    return (short)(u >> 16);
}
// short8 of bf16 -> 8 f32
__device__ __forceinline__ void b8tofs(const short8 v, float* f) {
    const unsigned* u = (const unsigned*)&v;
#pragma unroll
    for (int j = 0; j < 4; ++j) {
        f[2 * j]     = __builtin_bit_cast(float, u[j] << 16);
        f[2 * j + 1] = __builtin_bit_cast(float, u[j] & 0xffff0000u);
    }
}
// two short8 (same d-slice, rows j and j+64) -> f32x2 pairs {c_i, c_i64}
__device__ __forceinline__ void bpair(const short8 a, const short8 b, f32x2* p) {
    float fa[8], fb[8];
    b8tofs(a, fa); b8tofs(b, fb);
#pragma unroll
    for (int j = 0; j < 8; ++j) p[j] = f32x2{fa[j], fb[j]};
}
__device__ __forceinline__ f32x2 vabs2(f32x2 x) {
    u32x2 u = __builtin_bit_cast(u32x2, x);
    u &= 0x7fffffffu;
    return __builtin_bit_cast(f32x2, u);
}

// async global->LDS, 16B per lane. LDS dest = wave-uniform base + lane*16.
__device__ __forceinline__ void gll16(const void* g, void* l) {
    __builtin_amdgcn_global_load_lds(
        (const __attribute__((address_space(1))) int*)g,
        (__attribute__((address_space(3))) int*)l, 16, 0, 0);
}

// ---------------------------------------------------------------------------
// All input conversions in ONE kernel (r12/r16 verbatim).
// ---------------------------------------------------------------------------
__global__ __launch_bounds__(256)
void conv_all(const float* __restrict__ output, const float* __restrict__ context,
              const float* __restrict__ w1, const float* __restrict__ w2,
              const float* __restrict__ lin,
              short* __restrict__ ob16, short* __restrict__ cb16,
              short* __restrict__ w1t, short* __restrict__ w2t,
              short* __restrict__ lint)
{
    __shared__ float T[64][68];
    const int bid = blockIdx.x, tid = threadIdx.x;

    if (bid < 1024) {                       // straight convert, 8 floats/thread
        const int idx = bid * 256 + tid;
        const float* src; short* dst; int i;
        if (idx < (1 << 17)) { src = output;  dst = ob16; i = idx; }
        else                 { src = context; dst = cb16; i = idx - (1 << 17); }
        const float4* s4 = (const float4*)src + (long)i * 2;
        const float4 v0 = s4[0], v1 = s4[1];
        short8 r;
        r[0] = f2bf(v0.x); r[1] = f2bf(v0.y); r[2] = f2bf(v0.z); r[3] = f2bf(v0.w);
        r[4] = f2bf(v1.x); r[5] = f2bf(v1.y); r[6] = f2bf(v1.z); r[7] = f2bf(v1.w);
        *(short8*)(dst + (long)i * 8) = r;
        return;
    }

    const int tb = bid - 1024;
    const float* src; short* dst; long C, R; int t2;
    if (tb < 256)      { src = w1;  dst = w1t;  R = 1024; C = 1024; t2 = tb; }
    else if (tb < 512) { src = w2;  dst = w2t;  R = 1024; C = 1024; t2 = tb - 256; }
    else               { src = lin; dst = lint; R = 2048; C = 1024; t2 = tb - 512; }
    const int tr = t2 >> 4, tc = t2 & 15;
    const int r = tid >> 2, q = tid & 3;

    const float* s = src + (long)(tr * 64 + r) * C + tc * 64 + q * 16;
    const float4 a0 = ((const float4*)s)[0];
    const float4 a1 = ((const float4*)s)[1];
    const float4 a2 = ((const float4*)s)[2];
    const float4 a3 = ((const float4*)s)[3];
    *(float4*)&T[r][q * 16 + 0]  = a0;
    *(float4*)&T[r][q * 16 + 4]  = a1;
    *(float4*)&T[r][q * 16 + 8]  = a2;
    *(float4*)&T[r][q * 16 + 12] = a3;
    __syncthreads();

    short8 o0, o1;
#pragma unroll
    for (int j = 0; j < 8; ++j)  o0[j] = f2bf(T[q * 16 + j][r]);
#pragma unroll
    for (int j = 0; j < 8; ++j)  o1[j] = f2bf(T[q * 16 + 8 + j][r]);
    short* dp = dst + (long)(tc * 64 + r) * R + tr * 64 + q * 16;
    *(short8*)dp       = o0;
    *((short8*)dp + 1) = o1;
}

// ---------------------------------------------------------------------------
// Fused independent-GEMM job table (r16 verbatim): 64x64 tiles, 1024 blocks,
// 32KB LDS dbuf, gll16 + XOR chunk swizzle, XCD-aware tile order.
// ---------------------------------------------------------------------------
__global__ __launch_bounds__(256, 4)
void mm_jobs(const short* __restrict__ ob16, const short* __restrict__ cb16,
             const short* __restrict__ w1t, const short* __restrict__ w2t,
             const short* __restrict__ lint,
             const float* __restrict__ w_b, const float* __restrict__ lin_b,
             float* __restrict__ s_out, short* __restrict__ s_ctx16,
             float* __restrict__ outlin, short* __restrict__ ctxlin)
{
    __shared__ short As[2][64][64];
    __shared__ short Bs[2][64][64];
    const int tid = threadIdx.x;
    const int t = (blockIdx.x & 7) * 128 + (blockIdx.x >> 3);   // XCD swizzle
    const int lane = tid & 63, w = tid >> 6;

    const short *Ap, *Bp;
    int lda, ldb, bm, bn, ldc;
    const float* bias = nullptr;
    float* Cf = nullptr;
    short* Ch = nullptr;

    if (t < 768) {
        const int job = t >> 8, tl = t & 255;
        bm = (tl & 15) * 64;            // m fastest: B n-strip shared on-XCD
        bn = (tl >> 4) * 64;
        lda = 1024; ldb = 1024; ldc = 1024;
        if (job == 0)      { Ap = ob16; Bp = w1t;         bias = w_b;   Cf = s_out;   }
        else if (job == 1) { Ap = ob16; Bp = lint + 1024; ldb = 2048; bias = lin_b; Cf = outlin; }
        else               { Ap = cb16; Bp = w2t;                       Ch = s_ctx16; }
    } else {
        const int tl = t - 768, bz = tl >> 5, t2 = tl & 31;
        bm = (t2 & 15) * 64;            // m = d tiles
        bn = (t2 >> 4) * 64;            // n = i tiles (2)
        Ap = lint; lda = 2048;
        Bp = cb16 + (long)bz * (kI * kD); ldb = 1024;
        Ch = ctxlin + (long)bz * (kD * kI); ldc = 128;
    }

    const int m0 = (w >> 1) * 32, n0 = (w & 1) * 32;
    const int fr = lane & 15, fcol = lane >> 4, sl = lane & 7;
    const int r8 = lane >> 3;
    const int sw8 = ((lane & 7) ^ r8) * 8;   // swizzled source col (shorts)
    const int w16 = w * 16;

    f32x4 acc[2][2] = {};

    auto stage = [&](int buf, int k0) {      // 4 gll16 per wave
        const short* ga = Ap + (long)(bm + w16 + r8) * lda + k0 + sw8;
        gll16(ga,                 &As[buf][w16][0]);
        gll16(ga + 8 * (long)lda, &As[buf][w16 + 8][0]);
        const short* gb = Bp + (long)(bn + w16 + r8) * ldb + k0 + sw8;
        gll16(gb,                 &Bs[buf][w16][0]);
        gll16(gb + 8 * (long)ldb, &Bs[buf][w16 + 8][0]);
    };

    stage(0, 0);
    __syncthreads();
    int cur = 0;
    for (int s = 0; s < 16; ++s) {
        if (s < 15) stage(cur ^ 1, (s + 1) << 6);
#pragma unroll
        for (int ks8 = 0; ks8 < 8; ks8 += 4) {      // ks = 0, 32
            const int sa = ((ks8 + fcol) ^ sl) * 8; // swizzled read col (shorts)
            short8 a[2], b[2];
#pragma unroll
            for (int mi = 0; mi < 2; ++mi)
                a[mi] = *(const short8*)&As[cur][m0 + mi * 16 + fr][sa];
#pragma unroll
            for (int ni = 0; ni < 2; ++ni)
                b[ni] = *(const short8*)&Bs[cur][n0 + ni * 16 + fr][sa];
#pragma unroll
            for (int mi = 0; mi < 2; ++mi)
#pragma unroll
                for (int ni = 0; ni < 2; ++ni)
                    acc[mi][ni] = __builtin_amdgcn_mfma_f32_16x16x32_bf16(
                        a[mi], b[ni], acc[mi][ni], 0, 0, 0);
        }
        __syncthreads();
        cur ^= 1;
    }

    float bv[2] = {0, 0};
    if (bias) {
#pragma unroll
        for (int ni = 0; ni < 2; ++ni) bv[ni] = bias[bn + n0 + ni * 16 + fr];
    }
#pragma unroll
    for (int mi = 0; mi < 2; ++mi)
#pragma unroll
        for (int ni = 0; ni < 2; ++ni)
#pragma unroll
            for (int r = 0; r < 4; ++r) {
                const int row = bm + m0 + mi * 16 + ((lane >> 4) << 2) + r;
                const int col = bn + n0 + ni * 16 + fr;
                const float v = acc[mi][ni][r] + bv[ni];
                if (Ch) Ch[(long)row * ldc + col] = f2bf(v);
                else    Cf[(long)row * ldc + col] = v;
            }
}

// ---------------------------------------------------------------------------
// Fused score + mask + softmax + final GEMM, v7. Change vs r16: the score
// loop's Cs is privatized BY D-SLICE — wave wv stages only its own 16-d
// columns for all 128 i-rows into its own 8KB region (2 x 4KB slots; CsPool
// still 32KB total). No cross-wave LDS sharing in the loop -> all 16 in-loop
// __syncthreads replaced by the r16-verified per-wave counted-vmcnt pattern.
// The final GEMM (r16 pattern) uses the same per-wave region. Identical
// accumulation order (bpair) -> bit-identical numerics.
// ---------------------------------------------------------------------------
__global__ __launch_bounds__(256, 3)
void score_final(const float* __restrict__ s_out, const short* __restrict__ s_ctx16,
                 const float* __restrict__ score_w, const float* __restrict__ score_b,
                 const int* __restrict__ mask, const short* __restrict__ ctxlin,
                 const float* __restrict__ outlin, float* __restrict__ out_main,
                 float* __restrict__ attn_f32)
{
    __shared__ float As[2][1032];                   // 2 o-rows fp32 (8.25KB)
    __shared__ __align__(16) char CsPool[32768];    // 4 waves x 8KB private
    __shared__ short Wsh[1032];                     // score_w bf16 (2KB)
    __shared__ float Ps[4][2][128];                 // sa partials (4KB)
    __shared__ float Psi[4][128];                   // si partials (2KB)
    __shared__ float so_sh[2];
    __shared__ int   Msk[128];
    __shared__ __align__(16) short Pl[16][136];     // P rows padded to 16 (4.25KB)

    short* CsS = (short*)CsPool;
    const int b   = blockIdx.x;
    const int o0  = blockIdx.y * 2;
    const int tid = threadIdx.x;
    const int wv  = tid >> 6;          // d-quarter (wave-uniform)
    const int ln  = tid & 63;          // i low half; also owns i+64
    const int fr  = ln & 15, fg = ln >> 4;
    const int kb  = wv * 16;           // this wave's d-slice offset
    short* CsW = CsS + wv * 4096;      // per-wave 8KB region (shorts)

    const short* crow = s_ctx16 + (long)b * kI * kD;
    // stage chunk c's 16-d slice for all 128 rows into per-wave slot (4KB).
    // Lane l -> row it*32 + l/2, half l&1; dest linear = slot + it*512 + l*8.
    auto stageCs = [&](int slot, int c) {           // 4 gll16 per wave
        const int dc = c * 64;
        short* dst = CsW + slot * 2048;
#pragma unroll
        for (int it = 0; it < 4; ++it) {
            const int row  = it * 32 + (ln >> 1);
            const int half = ln & 1;
            gll16(crow + (long)row * kD + dc + kb + half * 8, dst + it * 512);
        }
    };

    stageCs(0, 0);                                  // in flight under prologue

    // ---- prologue: stage As (fp32), Wsh (bf16), Msk; zero Pl ----
    const float* arow = s_out + (long)(b * kO + o0) * kD;
#pragma unroll
    for (int q = 0; q < 2; ++q) {      // 2 rows x 1024 = 512 float4
        const int tq = tid + q * 256;
        const int rr = tq >> 8, c4 = (tq & 255) * 4;
        *(float4*)&As[rr][c4] = *(const float4*)&arow[(long)rr * kD + c4];
    }
    {
        const float4 w4 = *(const float4*)&score_w[tid * 4];
        const unsigned p0 = (unsigned)(unsigned short)f2bf(w4.x)
                          | ((unsigned)(unsigned short)f2bf(w4.y) << 16);
        const unsigned p1 = (unsigned)(unsigned short)f2bf(w4.z)
                          | ((unsigned)(unsigned short)f2bf(w4.w) << 16);
        *(u32x2*)&Wsh[tid * 4] = u32x2{p0, p1};
    }
    if (tid < 128) Msk[tid] = mask[b * kI + tid];
    {
        short* pf = &Pl[0][0];                      // 16*136 = 2176 shorts
        for (int j = tid; j < 272; j += 256) *(short8*)(pf + j * 8) = short8{};
    }
    __syncthreads();                   // drains vmcnt: chunk0 landed; LDS staged

    // ---- so[o] = sum_d s_out[o,d]*w[d]; waves 0,1 ----
    if (wv < 2) {
        const short8 wA = *(const short8*)&Wsh[ln * 16];
        const short8 wB = *(const short8*)&Wsh[ln * 16 + 8];
        float wf[16];
        b8tofs(wA, wf); b8tofs(wB, wf + 8);
        float acc = 0.0f;
#pragma unroll
        for (int q = 0; q < 4; ++q) {
            const float4 av = *(const float4*)&As[wv][ln * 16 + q * 4];
            acc = fmaf(av.x, wf[q*4+0], acc); acc = fmaf(av.y, wf[q*4+1], acc);
            acc = fmaf(av.z, wf[q*4+2], acc); acc = fmaf(av.w, wf[q*4+3], acc);
        }
#pragma unroll
        for (int d = 1; d < 64; d <<= 1) acc += __shfl_xor(acc, d, 64);
        if (ln == 0) so_sh[wv] = acc;
    }

    // ---- BARRIER-FREE score loop (per-wave private slots + counted vmcnt).
    // At iter c: stage chunk c+1 (4 loads), then vmcnt(4) retires chunk c's
    // 4 loads (oldest outstanding, FIFO). vmcnt(0) at the tail.
    f32x2 si2{0.0f, 0.0f};
    f32x2 sa2[2] = {f32x2{0.0f, 0.0f}, f32x2{0.0f, 0.0f}};

    for (int c = 0; c < 16; ++c) {
        if (c < 15) {
            stageCs((c + 1) & 1, c + 1);
            asm volatile("s_waitcnt vmcnt(4)" ::: "memory");
        } else {
            asm volatile("s_waitcnt vmcnt(0)" ::: "memory");
        }
        __builtin_amdgcn_sched_barrier(0);
        const int dc = c * 64;
        const short* Cw = CsW + (c & 1) * 2048;
        const short8 cA0 = *(const short8*)&Cw[ln * 16];          // row i, d 0..7
        const short8 cA1 = *(const short8*)&Cw[ln * 16 + 8];      // row i, d 8..15
        const short8 cB0 = *(const short8*)&Cw[(ln + 64) * 16];   // row i+64
        const short8 cB1 = *(const short8*)&Cw[(ln + 64) * 16 + 8];
        f32x2 c2[16];
        bpair(cA0, cB0, c2);
        bpair(cA1, cB1, c2 + 8);
        const short8 w0 = *(const short8*)&Wsh[dc + kb];      // broadcast
        const short8 w1 = *(const short8*)&Wsh[dc + kb + 8];
        float wr[16];
        b8tofs(w0, wr); b8tofs(w1, wr + 8);
        float av0[16], av1[16];
#pragma unroll
        for (int q = 0; q < 4; ++q) {
            *(float4*)&av0[q * 4] = *(const float4*)&As[0][dc + kb + q * 4];
            *(float4*)&av1[q * 4] = *(const float4*)&As[1][dc + kb + q * 4];
        }
#pragma unroll
        for (int d = 0; d < 16; ++d) {
            const f32x2 w2 = {wr[d], wr[d]};
            si2 += c2[d] * w2;
            const f32x2 x0 = c2[d] + f32x2{av0[d], av0[d]};
            const f32x2 x1 = c2[d] + f32x2{av1[d], av1[d]};
            sa2[0] += vabs2(x0) * w2;
            sa2[1] += vabs2(x1) * w2;
        }
    }

    // ---- stage final-GEMM B slot 0 (own region; hides under softmax) ----
    const short* ctxb = ctxlin + (long)b * (kD * kI);
    auto stageB = [&](int slot, int nc) {           // 4 gll16 per wave
        short* dst = CsW + slot * 2048;
#pragma unroll
        for (int it = 0; it < 4; ++it) {
            const int rl = it * 4 + (ln >> 4);      // row-local 0..15
            const int n  = nc * 64 + wv * 16 + rl;
            gll16(ctxb + (long)n * kI + ((ln & 15) ^ (rl & 7)) * 8,
                  dst + it * 512);
        }
    };
    stageB(0, 0);

#pragma unroll
    for (int o = 0; o < 2; ++o) {
        Ps[wv][o][ln]      = sa2[o].x;
        Ps[wv][o][ln + 64] = sa2[o].y;
    }
    Psi[wv][ln]      = si2.x;
    Psi[wv][ln + 64] = si2.y;
    __syncthreads();                   // partials visible; B slot0 landed

    // ---- combine + mask + softmax; waves 0,1 handle o-rows 0,1 ----
    if (wv < 2) {
        const int ow = wv;
        const float negInf = -__builtin_huge_valf();
        const float sb = score_b[0];
        const float siT0 = Psi[0][ln] + Psi[1][ln] + Psi[2][ln] + Psi[3][ln];
        const float siT1 = Psi[0][ln + 64] + Psi[1][ln + 64]
                         + Psi[2][ln + 64] + Psi[3][ln + 64];
        const float saT0 = Ps[0][ow][ln] + Ps[1][ow][ln]
                         + Ps[2][ow][ln] + Ps[3][ow][ln];
        const float saT1 = Ps[0][ow][ln + 64] + Ps[1][ow][ln + 64]
                         + Ps[2][ow][ln + 64] + Ps[3][ow][ln + 64];
        const float soV = so_sh[ow];
        float s0 = 0.505f * (soV + siT0) + 0.495f * saT0 + sb;
        float s1 = 0.505f * (soV + siT1) + 0.495f * saT1 + sb;
        if (Msk[ln]      != 0) s0 = negInf;
        if (Msk[ln + 64] != 0) s1 = negInf;

        float m = fmaxf(s0, s1);
#pragma unroll
        for (int d = 1; d < 64; d <<= 1) m = fmaxf(m, __shfl_xor(m, d, 64));
        const float e0 = __expf(s0 - m);
        const float e1 = __expf(s1 - m);
        float sum = e0 + e1;
#pragma unroll
        for (int d = 1; d < 64; d <<= 1) sum += __shfl_xor(sum, d, 64);
        const float inv = 1.0f / sum;

        const long rowoff = (long)(b * kO + o0 + ow) * kI;
        const float p0 = e0 * inv, p1 = e1 * inv;
        attn_f32[rowoff + ln]      = p0;
        attn_f32[rowoff + ln + 64] = p1;
        Pl[ow][ln]      = f2bf(p0);
        Pl[ow][ln + 64] = f2bf(p1);
    }
    __syncthreads();                   // Pl visible (drains vmcnt: slot0 ready)

    // ---- final GEMM: 16 steps of 64 n-rows, PER-WAVE barrier-free dbuf
    // (r16 pattern, per-wave region). Rows local 0..15 at CsW + slot*2048.
    for (int nc = 0; nc < 16; ++nc) {
        if (nc < 15) {
            stageB((nc + 1) & 1, nc + 1);
            asm volatile("s_waitcnt vmcnt(4)" ::: "memory");
        } else {
            asm volatile("s_waitcnt vmcnt(0)" ::: "memory");
        }
        __builtin_amdgcn_sched_barrier(0);
        const short* Bc = CsW + (nc & 1) * 2048;
        f32x4 acc{};
#pragma unroll
        for (int ks = 0; ks < 4; ++ks) {
            const short8 a = *(const short8*)&Pl[fr][ks * 32 + fg * 8];
            const int sc = ((ks * 4 + fg) ^ (fr & 7)) * 8;
            const short8 bb = *(const short8*)&Bc[fr * 128 + sc];
            acc = __builtin_amdgcn_mfma_f32_16x16x32_bf16(a, bb, acc, 0, 0, 0);
        }
        if (fg == 0) {                 // real P-rows are m = 0,1
#pragma unroll
            for (int r = 0; r < 2; ++r) {
                const int n = nc * 64 + wv * 16 + fr;
                const long off = (long)(b * kO + o0 + r) * kD + n;
                out_main[off] = leaky(acc[r] + outlin[off]);
            }
        }
    }
}

} // namespace

extern "C" void kernel_launch(void* const* d_in, const int* in_sizes, int n_in,
                              void* d_out, int out_size, void* d_ws, size_t ws_size,
                              hipStream_t stream)
{
    const float* output  = (const float*)d_in[0];   // [B,O,D]
    const float* context = (const float*)d_in[1];   // [B,I,D]
    const int*   mask    = (const int*)d_in[2];     // [B,I]
    const float* w_out_w = (const float*)d_in[3];   // [D,D]
    const float* w_ctx_w = (const float*)d_in[4];   // [D,D]
    const float* w_b     = (const float*)d_in[5];   // [D]
    const float* score_w = (const float*)d_in[6];   // [D]
    const float* score_b = (const float*)d_in[7];   // scalar
    const float* lin_w   = (const float*)d_in[8];   // [2D,D]
    const float* lin_b   = (const float*)d_in[9];   // [D]

    float* out_main = (float*)d_out;                 // [B,O,D]
    float* out_attn = out_main + kOutAttnOff;        // [B,O,I]
    float* s_out    = out_main;                      // overlay: block reads its 2
                                                     // rows before rewriting them

    char* wp = (char*)d_ws;
    short* s_ctx16 = (short*)wp;  wp += (size_t)2 << 20;  // s_ctx bf16 [B*I][D]
    short* ob16    = (short*)wp;  wp += (size_t)2 << 20;  // output bf16
    short* cb16    = (short*)wp;  wp += (size_t)2 << 20;  // context bf16
    short* w1t     = (short*)wp;  wp += (size_t)2 << 20;  // w_out_w^T bf16
    short* w2t     = (short*)wp;  wp += (size_t)2 << 20;  // w_ctx_w^T bf16
    short* lint    = (short*)wp;  wp += (size_t)4 << 20;  // lin_w^T bf16 [1024][2048]
    float* outlin  = (float*)wp;  wp += (size_t)4 << 20;  // output@lin_bot+lin_b fp32
    short* ctxlin  = (short*)wp;                          // (ctx@lin_top)^T bf16 [b][1024][128]

    const dim3 blk(256);

    // 1) all conversions
    hipLaunchKernelGGL(conv_all, dim3(2048), blk, 0, stream,
        output, context, w_out_w, w_ctx_w, lin_w, ob16, cb16, w1t, w2t, lint);

    // 2) all input-independent GEMMs: 64x64 tiles, 1024 blocks, XCD-swizzled
    hipLaunchKernelGGL(mm_jobs, dim3(1024), blk, 0, stream,
        ob16, cb16, w1t, w2t, lint, w_b, lin_b, s_out, s_ctx16, outlin, ctxlin);

    // 3) score + softmax + final GEMM fused (512 blocks, 3/CU, barrier-free loops)
    hipLaunchKernelGGL(score_final, dim3(8, 64), blk, 0, stream,
        s_out, s_ctx16, score_w, score_b, mask, ctxlin, outlin, out_main, out_attn);
}